// Round 6
// baseline (11293.222 us; speedup 1.0000x reference)
//
#include <hip/hip_runtime.h>
#include <math.h>

#define N_PTS 16384
#define N_CLUSTERS 4096
#define KNN_K 16
#define C_IN 64
#define C_OUT 128
#define FAN_IN 67
#define N_ROWS (N_CLUSTERS * KNN_K)   // 65536

// ---------------------------------------------------------------------------
// init: pp[i] = |pos_i|^2 (reference op order, no FMA), zero colsum/colsumsq
// ---------------------------------------------------------------------------
__global__ void init_kernel(const float* __restrict__ pos, float* __restrict__ pp,
                            float* __restrict__ cz) {
#pragma clang fp contract(off)
    int i = blockIdx.x * 256 + threadIdx.x;
    if (i < N_PTS) {
        float a = pos[i * 3 + 0], b = pos[i * 3 + 1], c = pos[i * 3 + 2];
        pp[i] = ((a * a) + (b * b)) + (c * c);
    }
    if (blockIdx.x == 0 && threadIdx.x < 256) cz[threadIdx.x] = 0.0f;
}

// ---------------------------------------------------------------------------
// bin: Morton-ordered spatial permutation + PLANAR float4 point array.
// 8x8x8 grid over clamp(floor(c+4),0..7), cells ranked by 9-bit Morton code
// (32 consecutive cells = compact 4x4x2 brick -> tight per-wave AABBs).
// Output pxyz[(j<<10)|t] = (x, y, z, orig_idx_bits) for FPS thread t's j-th
// point: lane-contiguous -> coalesced dwordx4 reads, 256 KB = L2-resident.
// ---------------------------------------------------------------------------
__global__ __launch_bounds__(1024) void bin_kernel(const float* __restrict__ pos,
                                                   float4* __restrict__ pxyz) {
    __shared__ int cnt[512];
    __shared__ int base[512];
    __shared__ int lperm[16384];
    const int t = threadIdx.x;
    if (t < 512) cnt[t] = 0;
    __syncthreads();
    int mycell[16];
#pragma unroll
    for (int j = 0; j < 16; ++j) {
        const int i = t * 16 + j;
        const float x = pos[i * 3 + 0], y = pos[i * 3 + 1], z = pos[i * 3 + 2];
        const int cx = min(7, max(0, (int)floorf(x + 4.0f)));
        const int cy = min(7, max(0, (int)floorf(y + 4.0f)));
        const int cz = min(7, max(0, (int)floorf(z + 4.0f)));
        // 9-bit Morton: spread 3 bits of each coord (b0->0, b1->3, b2->6)
        const int sx = (cx & 1) | ((cx & 2) << 2) | ((cx & 4) << 4);
        const int sy = (cy & 1) | ((cy & 2) << 2) | ((cy & 4) << 4);
        const int sz = (cz & 1) | ((cz & 2) << 2) | ((cz & 4) << 4);
        const int c = sx | (sy << 1) | (sz << 2);
        mycell[j] = c;
        atomicAdd(&cnt[c], 1);
    }
    __syncthreads();
    if (t < 512) base[t] = cnt[t];
    __syncthreads();
    for (int off = 1; off < 512; off <<= 1) {
        int v = 0;
        if (t < 512 && t >= off) v = base[t - off];
        __syncthreads();
        if (t < 512) base[t] += v;
        __syncthreads();
    }
    if (t < 512) { base[t] -= cnt[t]; cnt[t] = 0; }  // exclusive; reuse cnt as cursor
    __syncthreads();
#pragma unroll
    for (int j = 0; j < 16; ++j) {
        const int i = t * 16 + j;
        const int c = mycell[j];
        const int p = base[c] + atomicAdd(&cnt[c], 1);
        lperm[p] = i;
    }
    __syncthreads();
    // planar gather: thread t's j-th point -> pxyz[(j<<10)|t]
    for (int j = 0; j < 16; ++j) {
        const int i = lperm[(t << 4) | j];
        float4 q;
        q.x = pos[i * 3 + 0];
        q.y = pos[i * 3 + 1];
        q.z = pos[i * 3 + 2];
        q.w = __int_as_float(i);
        pxyz[(j << 10) | t] = q;
    }
}

// ---------------------------------------------------------------------------
// FPS v6: bucket-pruned, bit-exact, NO per-thread arrays in the register
// file (R3-R5 post-mortem: compiler spilled them to scratch -> 232 MB of
// L2/HBM spill traffic per dispatch dominated the critical path).
//   - point data: planar L2-resident pxyz (read only on the update path)
//   - md[16384] lives in LDS (lane-contiguous, conflict-free); dynamic
//     indexing legal -> unroll-4 update loop, ~45 live VGPRs, no spills
//   - AABB whole-wave skip, reference-exact update math, fused argmax with
//     min-orig-idx tie-break (oid rides in pxyz.w)
//   - one barrier/step: DPP wave reduce -> u64 LDS atomicMax key
//     (dist<<32 | (16383-oid)<<18 | wave<<4), per-wave candidate coords in
//     rotating s_cand slots, winner looked up entirely from LDS
// ---------------------------------------------------------------------------
__global__ __launch_bounds__(1024)
void fps_kernel(const float* __restrict__ pos, const float4* __restrict__ pxyz,
                int* __restrict__ clusters) {
#pragma clang fp contract(off)
    __shared__ float md_lds[16384];
    __shared__ unsigned long long s_key[4];
    __shared__ float s_cand[2][16][4];
    const int t = threadIdx.x;
    const int wv = t >> 6;

    // init md + per-thread AABB over its 16 Morton-local points
    float bnx = __builtin_inff(), bny = __builtin_inff(), bnz = __builtin_inff();
    float bxx = -__builtin_inff(), bxy = -__builtin_inff(), bxz = -__builtin_inff();
    for (int j = 0; j < 16; ++j) {
        const float4 q = pxyz[(j << 10) | t];
        md_lds[(j << 10) | t] = __builtin_inff();
        bnx = fminf(bnx, q.x); bxx = fmaxf(bxx, q.x);
        bny = fminf(bny, q.y); bxy = fmaxf(bxy, q.y);
        bnz = fminf(bnz, q.z); bxz = fmaxf(bxz, q.z);
    }
    float bv = __builtin_inff();       // cached per-thread max(md); inf => must update
    unsigned int mylo = 0;             // cached key low
    float cbx = 0.f, cby = 0.f, cbz = 0.f;  // cached candidate coords
    if (t == 0) clusters[0] = 0;
    if (t < 4) s_key[t] = 0ULL;
    float lx = pos[0], ly = pos[1], lz = pos[2];
    __syncthreads();

#define PAIR_STAGE(CTRL, RM)                                                          \
    do {                                                                              \
        unsigned int ohi = (unsigned int)__builtin_amdgcn_update_dpp(                 \
            0, (int)hi, (CTRL), (RM), 0xF, false);                                    \
        unsigned int olo = (unsigned int)__builtin_amdgcn_update_dpp(                 \
            0, (int)lo, (CTRL), (RM), 0xF, false);                                    \
        unsigned long long cur = ((unsigned long long)hi << 32) | lo;                 \
        unsigned long long oth = ((unsigned long long)ohi << 32) | olo;               \
        if (oth > cur) { hi = ohi; lo = olo; }                                        \
    } while (0)

    for (int step = 1; step < N_CLUSTERS; ++step) {
        // conservative squared distance from q to this thread's AABB
        const float dxl = fmaxf(fmaxf(bnx - lx, lx - bxx), 0.0f);
        const float dyl = fmaxf(fmaxf(bny - ly, ly - bxy), 0.0f);
        const float dzl = fmaxf(fmaxf(bnz - lz, lz - bxz), 0.0f);
        const float lb = ((dxl * dxl) + (dyl * dyl)) + (dzl * dzl);
        if (!(lb * 0.99998f >= bv)) {
            // update path: reference-exact min-distance refresh + fused
            // argmax with min-orig-idx tie-break
            float nb = 0.0f;
            int bo = 0x7fffffff;
            float sx = 0.f, sy = 0.f, sz = 0.f;
            for (int jj = 0; jj < 16; jj += 4) {
#pragma unroll
                for (int k = 0; k < 4; ++k) {
                    const int s = ((jj + k) << 10) | t;
                    const float4 q = pxyz[s];
                    const float dx = q.x - lx, dy = q.y - ly, dz = q.z - lz;
                    const float d = ((dx * dx) + (dy * dy)) + (dz * dz);
                    const float m = fminf(md_lds[s], d);
                    md_lds[s] = m;
                    const int oid = __float_as_int(q.w);
                    const bool sel = (m > nb) || ((m == nb) && (oid < bo));
                    nb = sel ? m : nb;
                    bo = sel ? oid : bo;
                    sx = sel ? q.x : sx;
                    sy = sel ? q.y : sy;
                    sz = sel ? q.z : sz;
                }
            }
            bv = nb;
            cbx = sx; cby = sy; cbz = sz;
            mylo = (((unsigned int)(16383 - bo)) << 18) | ((unsigned int)wv << 4);
        }

        // wave64 DPP pair-max on (dist_bits, lo); result lands in lane 63
        unsigned int hi = __float_as_uint(bv);
        unsigned int lo = mylo;
        PAIR_STAGE(0x111, 0xF);  // row_shr:1
        PAIR_STAGE(0x112, 0xF);  // row_shr:2
        PAIR_STAGE(0x114, 0xF);  // row_shr:4
        PAIR_STAGE(0x118, 0xF);  // row_shr:8
        PAIR_STAGE(0x142, 0xA);  // row_bcast:15 -> rows 1,3
        PAIR_STAGE(0x143, 0xC);  // row_bcast:31 -> rows 2,3

        const unsigned int wlo = (unsigned int)__builtin_amdgcn_readlane((int)lo, 63);
        if ((t & 63) == 63)
            atomicMax(&s_key[step & 3], (((unsigned long long)hi << 32) | lo));
        if (mylo == wlo) {  // this wave's winning lane (orig idx unique per lane)
            s_cand[step & 1][wv][0] = cbx;
            s_cand[step & 1][wv][1] = cby;
            s_cand[step & 1][wv][2] = cbz;
        }
        if (t == 0) s_key[(step + 2) & 3] = 0ULL;  // reset slot for step+2
        __syncthreads();

        const unsigned long long k = s_key[step & 3];
        const unsigned int klo = (unsigned int)k;
        if (t == 0) clusters[step] = (int)(16383u - (klo >> 18));
        const int wwin = (klo >> 4) & 15;
        lx = s_cand[step & 1][wwin][0];
        ly = s_cand[step & 1][wwin][1];
        lz = s_cand[step & 1][wwin][2];
    }
#undef PAIR_STAGE
}

// ---------------------------------------------------------------------------
// kNN: one block per cluster, 256 threads. d = (qq+pp) - 2*dot (dot FMA-
// ascending like BLAS), LDS distance array per 8192-chunk, 16 argmin rounds
// per chunk (tie -> lower index == stable top_k), exact merge of 2x16.
// Only the neighbor SET matters downstream.
// ---------------------------------------------------------------------------
__global__ __launch_bounds__(256) void knn_kernel(const float* __restrict__ pos,
                                                  const float* __restrict__ pp,
                                                  const int* __restrict__ clusters,
                                                  int* __restrict__ nbr) {
#pragma clang fp contract(off)
    __shared__ float s_d[8192];
    __shared__ float s_rv[4];
    __shared__ int   s_ri[4];
    __shared__ float s_tv[32];
    __shared__ int   s_ti[32];
    const int m = blockIdx.x, t = threadIdx.x;
    const int lane = t & 63, w = t >> 6;

    const int qi = clusters[m];
    const float qx = pos[qi * 3 + 0], qy = pos[qi * 3 + 1], qz = pos[qi * 3 + 2];
    const float qq = ((qx * qx) + (qy * qy)) + (qz * qz);

    for (int chunk = 0; chunk < 2; ++chunk) {
        const int base = chunk << 13;
        __syncthreads();  // protect s_d overwrite vs previous chunk's reads
        for (int i = t; i < 8192; i += 256) {
            const int p = base + i;
            float dot = fmaf(qx, pos[p * 3 + 0], 0.0f);
            dot = fmaf(qy, pos[p * 3 + 1], dot);
            dot = fmaf(qz, pos[p * 3 + 2], dot);
            s_d[i] = (qq + pp[p]) - 2.0f * dot;
        }
        __syncthreads();
        for (int r = 0; r < KNN_K; ++r) {
            float bv = __builtin_inff();
            int   bi = 0x7fffffff;
            for (int i = t; i < 8192; i += 256) {   // i ascending per thread
                float v = s_d[i];
                if (v < bv) { bv = v; bi = i; }     // strict < keeps first
            }
#pragma unroll
            for (int off = 32; off >= 1; off >>= 1) {
                float ov = __shfl_down(bv, off);
                int   oi = __shfl_down(bi, off);
                if (ov < bv || (ov == bv && oi < bi)) { bv = ov; bi = oi; }
            }
            if (lane == 0) { s_rv[w] = bv; s_ri[w] = bi; }
            __syncthreads();
            if (t == 0) {
                float fv = s_rv[0]; int fi = s_ri[0];
#pragma unroll
                for (int ww = 1; ww < 4; ++ww) {
                    if (s_rv[ww] < fv || (s_rv[ww] == fv && s_ri[ww] < fi)) {
                        fv = s_rv[ww]; fi = s_ri[ww];
                    }
                }
                s_tv[chunk * 16 + r] = fv;
                s_ti[chunk * 16 + r] = base + fi;
                s_d[fi] = __builtin_inff();
            }
            __syncthreads();
        }
    }
    if (t == 0) {   // exact merge of two sorted-by-(v,idx) lists
        int a = 0, b = 0;
        for (int r = 0; r < KNN_K; ++r) {
            bool takeA;
            if (b >= 16) takeA = true;
            else if (a >= 16) takeA = false;
            else {
                float va = s_tv[a], vb = s_tv[16 + b];
                takeA = (va < vb) || (va == vb && s_ti[a] < s_ti[16 + b]);
            }
            nbr[m * KNN_K + r] = takeA ? s_ti[a] : s_ti[16 + b];
            if (takeA) ++a; else ++b;
        }
    }
}

// ---------------------------------------------------------------------------
// MLP: grouped[r] = [pos[n]-pos[r>>4] (quirky full-pos indexing!), x[n]],
// h = grouped @ W^T.  PASS 1: accumulate column sum/sumsq.  PASS 2:
// recompute, y = scale*h+shift, out[m,c] = relu(max_k y) (relu∘max=max∘relu),
// plus sub_pos / sub_batch.  64 rows (= 4 whole clusters) x 128 cols / block.
// ---------------------------------------------------------------------------
template <int PASS>
__global__ __launch_bounds__(256) void mlp_kernel(const float* __restrict__ x,
                                                  const float* __restrict__ pos,
                                                  const int* __restrict__ nbr,
                                                  const float* __restrict__ W,
                                                  float* __restrict__ colsum,
                                                  float* __restrict__ colsumsq,
                                                  const float* __restrict__ ss,
                                                  const int* __restrict__ clusters,
                                                  const int* __restrict__ batch,
                                                  float* __restrict__ out) {
    __shared__ __align__(16) float At[FAN_IN][68];     // [i][r], pad 68
    __shared__ __align__(16) float Wl[FAN_IN * 132];   // [i][c], pad 132
    __shared__ float red0[128], red1[128];
    __shared__ float hm[8][132];                       // pass2 half-cluster maxima
    const int tid = threadIdx.x;
    const int R0 = blockIdx.x * 64;

    // stage W transposed
    for (int idx = tid; idx < FAN_IN * 128; idx += 256) {
        int i = idx >> 7, c = idx & 127;
        Wl[i * 132 + c] = W[c * FAN_IN + i];
    }
    // stage A transposed (gather)
    {
        const int wv = tid >> 6, lane = tid & 63;
        for (int r = wv; r < 64; r += 4) {
            const int R = R0 + r;
            const int n = nbr[R];
            At[3 + lane][r] = x[n * C_IN + lane];
            if (lane < 3) {
                const int q = R >> 4;  // faithful to source: cluster ORDINAL indexes pos
                At[lane][r] = pos[n * 3 + lane] - pos[q * 3 + lane];
            }
        }
    }
    if (PASS == 1 && tid < 128) { red0[tid] = 0.0f; red1[tid] = 0.0f; }
    __syncthreads();

    const int g = tid & 31, rg = tid >> 5;
    const int c0 = g * 4, r0 = rg * 8;
    float acc[8][4];
#pragma unroll
    for (int a = 0; a < 8; ++a)
#pragma unroll
        for (int b = 0; b < 4; ++b) acc[a][b] = 0.0f;

    for (int i = 0; i < FAN_IN; ++i) {
        const float4 w4 = *(const float4*)&Wl[i * 132 + c0];
        const float4 a0 = *(const float4*)&At[i][r0];
        const float4 a1 = *(const float4*)&At[i][r0 + 4];
        const float av[8] = {a0.x, a0.y, a0.z, a0.w, a1.x, a1.y, a1.z, a1.w};
        const float wv4[4] = {w4.x, w4.y, w4.z, w4.w};
#pragma unroll
        for (int a = 0; a < 8; ++a)
#pragma unroll
            for (int b = 0; b < 4; ++b) acc[a][b] = fmaf(av[a], wv4[b], acc[a][b]);
    }

    if (PASS == 1) {
#pragma unroll
        for (int b = 0; b < 4; ++b) {
            float s = 0.0f, sq = 0.0f;
#pragma unroll
            for (int a = 0; a < 8; ++a) {
                s += acc[a][b];
                sq = fmaf(acc[a][b], acc[a][b], sq);
            }
            atomicAdd(&red0[c0 + b], s);
            atomicAdd(&red1[c0 + b], sq);
        }
        __syncthreads();
        if (tid < 128) {
            atomicAdd(&colsum[tid], red0[tid]);
            atomicAdd(&colsumsq[tid], red1[tid]);
        }
    } else {
        // rows r0..r0+7 lie in ONE cluster (half of it): reduce then combine
#pragma unroll
        for (int b = 0; b < 4; ++b) {
            const float sc = ss[c0 + b], sh = ss[128 + c0 + b];
            float mx = -__builtin_inff();
#pragma unroll
            for (int a = 0; a < 8; ++a) mx = fmaxf(mx, fmaf(sc, acc[a][b], sh));
            hm[rg][c0 + b] = mx;
        }
        __syncthreads();
        for (int o = tid; o < 512; o += 256) {
            const int cl = o >> 7, c = o & 127;
            const float v = fmaxf(hm[2 * cl][c], hm[2 * cl + 1][c]);
            const int M = blockIdx.x * 4 + cl;
            out[M * 128 + c] = fmaxf(v, 0.0f);
        }
        if (tid < 12) {
            const int cl = tid / 3, l = tid % 3;
            const int M = blockIdx.x * 4 + cl;
            out[524288 + M * 3 + l] = pos[clusters[M] * 3 + l];
        } else if (tid < 16) {
            const int M = blockIdx.x * 4 + (tid - 12);
            out[536576 + M] = (float)batch[clusters[M]];
        }
    }
}

// ---------------------------------------------------------------------------
// stats: scale/shift from column sums (biased var, like torch BN training)
// ---------------------------------------------------------------------------
__global__ void stats_kernel(const float* __restrict__ colsum,
                             const float* __restrict__ colsumsq,
                             const float* __restrict__ gamma,
                             const float* __restrict__ beta,
                             float* __restrict__ ss) {
    const int c = threadIdx.x;
    const float inv_n = 1.0f / (float)N_ROWS;
    const float mean = colsum[c] * inv_n;
    float var = colsumsq[c] * inv_n - mean * mean;
    var = fmaxf(var, 0.0f);
    const float inv = rsqrtf(var + 1e-5f);
    const float sc = gamma[c] * inv;
    ss[c] = sc;
    ss[128 + c] = beta[c] - mean * sc;
}

// ---------------------------------------------------------------------------
extern "C" void kernel_launch(void* const* d_in, const int* in_sizes, int n_in,
                              void* d_out, int out_size, void* d_ws, size_t ws_size,
                              hipStream_t stream) {
    const float* x     = (const float*)d_in[0];
    const float* pos   = (const float*)d_in[1];
    const int*   batch = (const int*)d_in[2];
    const float* W     = (const float*)d_in[3];
    const float* gamma = (const float*)d_in[4];
    const float* beta  = (const float*)d_in[5];
    float* out = (float*)d_out;
    float* wsf = (float*)d_ws;

    float4* pxyz    = (float4*)d_ws;          // [16384] float4 = 262144 B (16B-aligned at base)
    int*   clusters = (int*)d_ws + 65536;     // [4096]
    int*   nbr      = clusters + 4096;        // [65536]
    float* pp       = wsf + 135168;           // [16384]
    float* colsum   = wsf + 151552;           // [128]
    float* colsumsq = wsf + 151680;           // [128]
    float* ss       = wsf + 151808;           // [256]

    init_kernel<<<dim3(64), dim3(256), 0, stream>>>(pos, pp, colsum);
    bin_kernel<<<dim3(1), dim3(1024), 0, stream>>>(pos, pxyz);
    fps_kernel<<<dim3(1), dim3(1024), 0, stream>>>(pos, pxyz, clusters);
    knn_kernel<<<dim3(N_CLUSTERS), dim3(256), 0, stream>>>(pos, pp, clusters, nbr);
    mlp_kernel<1><<<dim3(1024), dim3(256), 0, stream>>>(x, pos, nbr, W, colsum, colsumsq,
                                                        ss, clusters, batch, out);
    stats_kernel<<<dim3(1), dim3(128), 0, stream>>>(colsum, colsumsq, gamma, beta, ss);
    mlp_kernel<2><<<dim3(1024), dim3(256), 0, stream>>>(x, pos, nbr, W, colsum, colsumsq,
                                                        ss, clusters, batch, out);
}

// Round 8
// 9055.869 us; speedup vs baseline: 1.2471x; 1.2471x over previous
//
#include <hip/hip_runtime.h>
#include <math.h>

#define N_PTS 16384
#define N_CLUSTERS 4096
#define KNN_K 16
#define C_IN 64
#define C_OUT 128
#define FAN_IN 67
#define N_ROWS (N_CLUSTERS * KNN_K)   // 65536

// ---------------------------------------------------------------------------
// init: pp[i] = |pos_i|^2 (reference op order, no FMA), zero colsum/colsumsq
// ---------------------------------------------------------------------------
__global__ void init_kernel(const float* __restrict__ pos, float* __restrict__ pp,
                            float* __restrict__ cz) {
#pragma clang fp contract(off)
    int i = blockIdx.x * 256 + threadIdx.x;
    if (i < N_PTS) {
        float a = pos[i * 3 + 0], b = pos[i * 3 + 1], c = pos[i * 3 + 2];
        pp[i] = ((a * a) + (b * b)) + (c * c);
    }
    if (blockIdx.x == 0 && threadIdx.x < 256) cz[threadIdx.x] = 0.0f;
}

// ---------------------------------------------------------------------------
// bin: Morton-ordered spatial permutation + PLANAR float4 point array.
// 8x8x8 grid over clamp(floor(c+4),0..7), cells ranked by 9-bit Morton code.
// pxyz[(j<<10)|t] = (x, y, z, orig_idx_bits) for FPS thread t's j-th point:
// lane-contiguous -> coalesced dwordx4 reads, 256 KB = L2-resident.
// ---------------------------------------------------------------------------
__global__ __launch_bounds__(1024) void bin_kernel(const float* __restrict__ pos,
                                                   float4* __restrict__ pxyz) {
    __shared__ int cnt[512];
    __shared__ int base[512];
    __shared__ int lperm[16384];
    const int t = threadIdx.x;
    if (t < 512) cnt[t] = 0;
    __syncthreads();
    int mycell[16];
#pragma unroll
    for (int j = 0; j < 16; ++j) {
        const int i = t * 16 + j;
        const float x = pos[i * 3 + 0], y = pos[i * 3 + 1], z = pos[i * 3 + 2];
        const int cx = min(7, max(0, (int)floorf(x + 4.0f)));
        const int cy = min(7, max(0, (int)floorf(y + 4.0f)));
        const int cz = min(7, max(0, (int)floorf(z + 4.0f)));
        const int sx = (cx & 1) | ((cx & 2) << 2) | ((cx & 4) << 4);
        const int sy = (cy & 1) | ((cy & 2) << 2) | ((cy & 4) << 4);
        const int sz = (cz & 1) | ((cz & 2) << 2) | ((cz & 4) << 4);
        const int c = sx | (sy << 1) | (sz << 2);
        mycell[j] = c;
        atomicAdd(&cnt[c], 1);
    }
    __syncthreads();
    if (t < 512) base[t] = cnt[t];
    __syncthreads();
    for (int off = 1; off < 512; off <<= 1) {
        int v = 0;
        if (t < 512 && t >= off) v = base[t - off];
        __syncthreads();
        if (t < 512) base[t] += v;
        __syncthreads();
    }
    if (t < 512) { base[t] -= cnt[t]; cnt[t] = 0; }  // exclusive; reuse cnt as cursor
    __syncthreads();
#pragma unroll
    for (int j = 0; j < 16; ++j) {
        const int i = t * 16 + j;
        const int c = mycell[j];
        const int p = base[c] + atomicAdd(&cnt[c], 1);
        lperm[p] = i;
    }
    __syncthreads();
    for (int j = 0; j < 16; ++j) {
        const int i = lperm[(t << 4) | j];
        float4 q;
        q.x = pos[i * 3 + 0];
        q.y = pos[i * 3 + 1];
        q.z = pos[i * 3 + 2];
        q.w = __int_as_float(i);
        pxyz[(j << 10) | t] = q;
    }
}

// ---------------------------------------------------------------------------
// FPS v8: stale-slot reduce, FIXED. R7 bug: the DPP reduce ran under a
// per-thread exec mask, so a partially-updating wave republished its slot as
// the max over updating lanes only (skipped lanes' cached maxima dropped).
// Fix: wave-uniform branch via __any(need); only need-lanes refresh md and
// their cached candidate (mylo/coords), then ALL 64 lanes reduce cached-or-
// fresh (bv, mylo) and the winning lane republishes. Slot invariant (= true
// wave max) restored; skipping waves still bypass everything.
//   phase A (all waves): lanes<16 read 16 persistent slots, 4-stage shfl_xor
//     butterfly -> winner; coords via broadcast LDS reads.      [barrier]
//   phase B: AABB skip test; if __any lane needs it: masked md refresh
//     (2x8-wide pxyz loads), full-wave DPP reduce, publish.     [barrier]
// Bit-exact: same d expression/order (contract off), min-orig-idx tie-break
// in key, conservative skip margin (proof in R3 notes).
// ---------------------------------------------------------------------------
__global__ __launch_bounds__(1024)
__attribute__((amdgpu_waves_per_eu(4, 4)))
void fps_kernel(const float* __restrict__ pos, const float4* __restrict__ pxyz,
                int* __restrict__ clusters) {
#pragma clang fp contract(off)
    __shared__ float md[16384];
    __shared__ unsigned long long skey[16];
    __shared__ __align__(16) float scand[16][4];
    const int t = threadIdx.x;
    const int wv = t >> 6;
    const int lane = t & 63;

    // per-thread AABB over its 16 Morton-local points; md init
    float bnx = __builtin_inff(), bny = __builtin_inff(), bnz = __builtin_inff();
    float bxx = -__builtin_inff(), bxy = -__builtin_inff(), bxz = -__builtin_inff();
    for (int j = 0; j < 16; ++j) {
        const float4 q = pxyz[(j << 10) | t];
        md[(j << 10) | t] = __builtin_inff();
        bnx = fminf(bnx, q.x); bxx = fmaxf(bxx, q.x);
        bny = fminf(bny, q.y); bxy = fmaxf(bxy, q.y);
        bnz = fminf(bnz, q.z); bxz = fmaxf(bxz, q.z);
    }
    if (t == 0) clusters[0] = 0;
    float lx = pos[0], ly = pos[1], lz = pos[2];
    float bv = 0.0f;                        // cached per-thread max(md)
    unsigned int mylo = 0;                  // cached key low (candidate id + wave)
    float cbx = 0.f, cby = 0.f, cbz = 0.f;  // cached candidate coords
    __syncthreads();

#define PAIR_STAGE(CTRL, RM)                                                          \
    do {                                                                              \
        unsigned int ohi = (unsigned int)__builtin_amdgcn_update_dpp(                 \
            0, (int)hi, (CTRL), (RM), 0xF, false);                                    \
        unsigned int olo = (unsigned int)__builtin_amdgcn_update_dpp(                 \
            0, (int)lo, (CTRL), (RM), 0xF, false);                                    \
        unsigned long long cur = ((unsigned long long)hi << 32) | lo;                 \
        unsigned long long oth = ((unsigned long long)ohi << 32) | olo;               \
        if (oth > cur) { hi = ohi; lo = olo; }                                        \
    } while (0)

// per-thread md refresh + cached-candidate recompute (call under `need` mask)
#define REFRESH_THREAD()                                                              \
    do {                                                                              \
        float nb = 0.0f;                                                              \
        int bo = 0x7fffffff;                                                          \
        float sx = 0.f, sy = 0.f, sz = 0.f;                                           \
        _Pragma("unroll")                                                             \
        for (int h = 0; h < 2; ++h) {                                                 \
            float4 q[8];                                                              \
            _Pragma("unroll")                                                         \
            for (int k = 0; k < 8; ++k) q[k] = pxyz[(((h << 3) + k) << 10) | t];      \
            _Pragma("unroll")                                                         \
            for (int k = 0; k < 8; ++k) {                                             \
                const int s = (((h << 3) + k) << 10) | t;                             \
                const float dx = q[k].x - lx, dy = q[k].y - ly, dz = q[k].z - lz;     \
                const float d = ((dx * dx) + (dy * dy)) + (dz * dz);                  \
                const float m = fminf(md[s], d);                                      \
                md[s] = m;                                                            \
                const int oid = __float_as_int(q[k].w);                               \
                const bool sel = (m > nb) || ((m == nb) && (oid < bo));               \
                nb = sel ? m : nb;                                                    \
                bo = sel ? oid : bo;                                                  \
                sx = sel ? q[k].x : sx;                                               \
                sy = sel ? q[k].y : sy;                                               \
                sz = sel ? q[k].z : sz;                                               \
            }                                                                         \
        }                                                                             \
        bv = nb;                                                                      \
        cbx = sx; cby = sy; cbz = sz;                                                 \
        mylo = (((unsigned int)(16383 - bo)) << 18) | ((unsigned int)wv << 4);        \
    } while (0)

// full-wave reduce over cached (bv, mylo); winning lane republishes the slot
#define REDUCE_AND_PUBLISH()                                                          \
    do {                                                                              \
        unsigned int hi = __float_as_uint(bv), lo = mylo;                             \
        PAIR_STAGE(0x111, 0xF);                                                       \
        PAIR_STAGE(0x112, 0xF);                                                       \
        PAIR_STAGE(0x114, 0xF);                                                       \
        PAIR_STAGE(0x118, 0xF);                                                       \
        PAIR_STAGE(0x142, 0xA);                                                       \
        PAIR_STAGE(0x143, 0xC);                                                       \
        const unsigned int wl = (unsigned int)__builtin_amdgcn_readlane((int)lo, 63); \
        const unsigned int wh = (unsigned int)__builtin_amdgcn_readlane((int)hi, 63); \
        if (mylo == wl && __float_as_uint(bv) == wh) {                                \
            skey[wv] = (((unsigned long long)wh) << 32) | wl;                         \
            scand[wv][0] = cbx; scand[wv][1] = cby; scand[wv][2] = cbz;               \
        }                                                                             \
    } while (0)

    // initial update vs point 0 -> all 16 slots valid
    REFRESH_THREAD();
    REDUCE_AND_PUBLISH();
    __syncthreads();

    for (int step = 1; step < N_CLUSTERS; ++step) {
        // ---- phase A: pick winner from the 16 persistent slots ----
        unsigned long long kk = 0ULL;
        if (lane < 16) kk = skey[lane];
        unsigned int khi = (unsigned int)(kk >> 32), klo = (unsigned int)kk;
#pragma unroll
        for (int m = 1; m <= 8; m <<= 1) {
            const unsigned int ohi = (unsigned int)__shfl_xor((int)khi, m);
            const unsigned int olo = (unsigned int)__shfl_xor((int)klo, m);
            const unsigned long long cur = (((unsigned long long)khi) << 32) | klo;
            const unsigned long long oth = (((unsigned long long)ohi) << 32) | olo;
            if (oth > cur) { khi = ohi; klo = olo; }
        }
        klo = (unsigned int)__builtin_amdgcn_readfirstlane((int)klo);
        if (t == 0) clusters[step] = (int)(16383u - (klo >> 18));
        const int wwin = (klo >> 4) & 15;
        lx = scand[wwin][0];   // broadcast reads (same addr all lanes)
        ly = scand[wwin][1];
        lz = scand[wwin][2];
        __syncthreads();       // barrier A: slot reads done before any rewrite

        // ---- phase B: conservative AABB skip, wave-uniform update ----
        const float dxl = fmaxf(fmaxf(bnx - lx, lx - bxx), 0.0f);
        const float dyl = fmaxf(fmaxf(bny - ly, ly - bxy), 0.0f);
        const float dzl = fmaxf(fmaxf(bnz - lz, lz - bxz), 0.0f);
        const float lb = ((dxl * dxl) + (dyl * dyl)) + (dzl * dzl);
        const bool need = !(lb * 0.99998f >= bv);
        if (__any(need)) {
            if (need) {
                REFRESH_THREAD();
            }
            REDUCE_AND_PUBLISH();   // ALL 64 lanes: cached-or-fresh values
        }
        __syncthreads();       // barrier B: publishes visible to next phase A
    }
#undef REDUCE_AND_PUBLISH
#undef REFRESH_THREAD
#undef PAIR_STAGE
}

// ---------------------------------------------------------------------------
// kNN: one block per cluster, 256 threads. d = (qq+pp) - 2*dot (dot FMA-
// ascending like BLAS), LDS distance array per 8192-chunk, 16 argmin rounds
// per chunk (tie -> lower index == stable top_k), exact merge of 2x16.
// Only the neighbor SET matters downstream.
// ---------------------------------------------------------------------------
__global__ __launch_bounds__(256) void knn_kernel(const float* __restrict__ pos,
                                                  const float* __restrict__ pp,
                                                  const int* __restrict__ clusters,
                                                  int* __restrict__ nbr) {
#pragma clang fp contract(off)
    __shared__ float s_d[8192];
    __shared__ float s_rv[4];
    __shared__ int   s_ri[4];
    __shared__ float s_tv[32];
    __shared__ int   s_ti[32];
    const int m = blockIdx.x, t = threadIdx.x;
    const int lane = t & 63, w = t >> 6;

    const int qi = clusters[m];
    const float qx = pos[qi * 3 + 0], qy = pos[qi * 3 + 1], qz = pos[qi * 3 + 2];
    const float qq = ((qx * qx) + (qy * qy)) + (qz * qz);

    for (int chunk = 0; chunk < 2; ++chunk) {
        const int base = chunk << 13;
        __syncthreads();  // protect s_d overwrite vs previous chunk's reads
        for (int i = t; i < 8192; i += 256) {
            const int p = base + i;
            float dot = fmaf(qx, pos[p * 3 + 0], 0.0f);
            dot = fmaf(qy, pos[p * 3 + 1], dot);
            dot = fmaf(qz, pos[p * 3 + 2], dot);
            s_d[i] = (qq + pp[p]) - 2.0f * dot;
        }
        __syncthreads();
        for (int r = 0; r < KNN_K; ++r) {
            float bv = __builtin_inff();
            int   bi = 0x7fffffff;
            for (int i = t; i < 8192; i += 256) {   // i ascending per thread
                float v = s_d[i];
                if (v < bv) { bv = v; bi = i; }     // strict < keeps first
            }
#pragma unroll
            for (int off = 32; off >= 1; off >>= 1) {
                float ov = __shfl_down(bv, off);
                int   oi = __shfl_down(bi, off);
                if (ov < bv || (ov == bv && oi < bi)) { bv = ov; bi = oi; }
            }
            if (lane == 0) { s_rv[w] = bv; s_ri[w] = bi; }
            __syncthreads();
            if (t == 0) {
                float fv = s_rv[0]; int fi = s_ri[0];
#pragma unroll
                for (int ww = 1; ww < 4; ++ww) {
                    if (s_rv[ww] < fv || (s_rv[ww] == fv && s_ri[ww] < fi)) {
                        fv = s_rv[ww]; fi = s_ri[ww];
                    }
                }
                s_tv[chunk * 16 + r] = fv;
                s_ti[chunk * 16 + r] = base + fi;
                s_d[fi] = __builtin_inff();
            }
            __syncthreads();
        }
    }
    if (t == 0) {   // exact merge of two sorted-by-(v,idx) lists
        int a = 0, b = 0;
        for (int r = 0; r < KNN_K; ++r) {
            bool takeA;
            if (b >= 16) takeA = true;
            else if (a >= 16) takeA = false;
            else {
                float va = s_tv[a], vb = s_tv[16 + b];
                takeA = (va < vb) || (va == vb && s_ti[a] < s_ti[16 + b]);
            }
            nbr[m * KNN_K + r] = takeA ? s_ti[a] : s_ti[16 + b];
            if (takeA) ++a; else ++b;
        }
    }
}

// ---------------------------------------------------------------------------
// MLP: grouped[r] = [pos[n]-pos[r>>4] (quirky full-pos indexing!), x[n]],
// h = grouped @ W^T.  PASS 1: accumulate column sum/sumsq.  PASS 2:
// recompute, y = scale*h+shift, out[m,c] = relu(max_k y) (relu∘max=max∘relu),
// plus sub_pos / sub_batch.  64 rows (= 4 whole clusters) x 128 cols / block.
// ---------------------------------------------------------------------------
template <int PASS>
__global__ __launch_bounds__(256) void mlp_kernel(const float* __restrict__ x,
                                                  const float* __restrict__ pos,
                                                  const int* __restrict__ nbr,
                                                  const float* __restrict__ W,
                                                  float* __restrict__ colsum,
                                                  float* __restrict__ colsumsq,
                                                  const float* __restrict__ ss,
                                                  const int* __restrict__ clusters,
                                                  const int* __restrict__ batch,
                                                  float* __restrict__ out) {
    __shared__ __align__(16) float At[FAN_IN][68];     // [i][r], pad 68
    __shared__ __align__(16) float Wl[FAN_IN * 132];   // [i][c], pad 132
    __shared__ float red0[128], red1[128];
    __shared__ float hm[8][132];                       // pass2 half-cluster maxima
    const int tid = threadIdx.x;
    const int R0 = blockIdx.x * 64;

    // stage W transposed
    for (int idx = tid; idx < FAN_IN * 128; idx += 256) {
        int i = idx >> 7, c = idx & 127;
        Wl[i * 132 + c] = W[c * FAN_IN + i];
    }
    // stage A transposed (gather)
    {
        const int wv = tid >> 6, lane = tid & 63;
        for (int r = wv; r < 64; r += 4) {
            const int R = R0 + r;
            const int n = nbr[R];
            At[3 + lane][r] = x[n * C_IN + lane];
            if (lane < 3) {
                const int q = R >> 4;  // faithful to source: cluster ORDINAL indexes pos
                At[lane][r] = pos[n * 3 + lane] - pos[q * 3 + lane];
            }
        }
    }
    if (PASS == 1 && tid < 128) { red0[tid] = 0.0f; red1[tid] = 0.0f; }
    __syncthreads();

    const int g = tid & 31, rg = tid >> 5;
    const int c0 = g * 4, r0 = rg * 8;
    float acc[8][4];
#pragma unroll
    for (int a = 0; a < 8; ++a)
#pragma unroll
        for (int b = 0; b < 4; ++b) acc[a][b] = 0.0f;

    for (int i = 0; i < FAN_IN; ++i) {
        const float4 w4 = *(const float4*)&Wl[i * 132 + c0];
        const float4 a0 = *(const float4*)&At[i][r0];
        const float4 a1 = *(const float4*)&At[i][r0 + 4];
        const float av[8] = {a0.x, a0.y, a0.z, a0.w, a1.x, a1.y, a1.z, a1.w};
        const float wv4[4] = {w4.x, w4.y, w4.z, w4.w};
#pragma unroll
        for (int a = 0; a < 8; ++a)
#pragma unroll
            for (int b = 0; b < 4; ++b) acc[a][b] = fmaf(av[a], wv4[b], acc[a][b]);
    }

    if (PASS == 1) {
#pragma unroll
        for (int b = 0; b < 4; ++b) {
            float s = 0.0f, sq = 0.0f;
#pragma unroll
            for (int a = 0; a < 8; ++a) {
                s += acc[a][b];
                sq = fmaf(acc[a][b], acc[a][b], sq);
            }
            atomicAdd(&red0[c0 + b], s);
            atomicAdd(&red1[c0 + b], sq);
        }
        __syncthreads();
        if (tid < 128) {
            atomicAdd(&colsum[tid], red0[tid]);
            atomicAdd(&colsumsq[tid], red1[tid]);
        }
    } else {
        // rows r0..r0+7 lie in ONE cluster (half of it): reduce then combine
#pragma unroll
        for (int b = 0; b < 4; ++b) {
            const float sc = ss[c0 + b], sh = ss[128 + c0 + b];
            float mx = -__builtin_inff();
#pragma unroll
            for (int a = 0; a < 8; ++a) mx = fmaxf(mx, fmaf(sc, acc[a][b], sh));
            hm[rg][c0 + b] = mx;
        }
        __syncthreads();
        for (int o = tid; o < 512; o += 256) {
            const int cl = o >> 7, c = o & 127;
            const float v = fmaxf(hm[2 * cl][c], hm[2 * cl + 1][c]);
            const int M = blockIdx.x * 4 + cl;
            out[M * 128 + c] = fmaxf(v, 0.0f);
        }
        if (tid < 12) {
            const int cl = tid / 3, l = tid % 3;
            const int M = blockIdx.x * 4 + cl;
            out[524288 + M * 3 + l] = pos[clusters[M] * 3 + l];
        } else if (tid < 16) {
            const int M = blockIdx.x * 4 + (tid - 12);
            out[536576 + M] = (float)batch[clusters[M]];
        }
    }
}

// ---------------------------------------------------------------------------
// stats: scale/shift from column sums (biased var, like torch BN training)
// ---------------------------------------------------------------------------
__global__ void stats_kernel(const float* __restrict__ colsum,
                             const float* __restrict__ colsumsq,
                             const float* __restrict__ gamma,
                             const float* __restrict__ beta,
                             float* __restrict__ ss) {
    const int c = threadIdx.x;
    const float inv_n = 1.0f / (float)N_ROWS;
    const float mean = colsum[c] * inv_n;
    float var = colsumsq[c] * inv_n - mean * mean;
    var = fmaxf(var, 0.0f);
    const float inv = rsqrtf(var + 1e-5f);
    const float sc = gamma[c] * inv;
    ss[c] = sc;
    ss[128 + c] = beta[c] - mean * sc;
}

// ---------------------------------------------------------------------------
extern "C" void kernel_launch(void* const* d_in, const int* in_sizes, int n_in,
                              void* d_out, int out_size, void* d_ws, size_t ws_size,
                              hipStream_t stream) {
    const float* x     = (const float*)d_in[0];
    const float* pos   = (const float*)d_in[1];
    const int*   batch = (const int*)d_in[2];
    const float* W     = (const float*)d_in[3];
    const float* gamma = (const float*)d_in[4];
    const float* beta  = (const float*)d_in[5];
    float* out = (float*)d_out;
    float* wsf = (float*)d_ws;

    float4* pxyz    = (float4*)d_ws;          // [16384] float4 = 262144 B
    int*   clusters = (int*)d_ws + 65536;     // [4096]
    int*   nbr      = clusters + 4096;        // [65536]
    float* pp       = wsf + 135168;           // [16384]
    float* colsum   = wsf + 151552;           // [128]
    float* colsumsq = wsf + 151680;           // [128]
    float* ss       = wsf + 151808;           // [256]

    init_kernel<<<dim3(64), dim3(256), 0, stream>>>(pos, pp, colsum);
    bin_kernel<<<dim3(1), dim3(1024), 0, stream>>>(pos, pxyz);
    fps_kernel<<<dim3(1), dim3(1024), 0, stream>>>(pos, pxyz, clusters);
    knn_kernel<<<dim3(N_CLUSTERS), dim3(256), 0, stream>>>(pos, pp, clusters, nbr);
    mlp_kernel<1><<<dim3(1024), dim3(256), 0, stream>>>(x, pos, nbr, W, colsum, colsumsq,
                                                        ss, clusters, batch, out);
    stats_kernel<<<dim3(1), dim3(128), 0, stream>>>(colsum, colsumsq, gamma, beta, ss);
    mlp_kernel<2><<<dim3(1024), dim3(256), 0, stream>>>(x, pos, nbr, W, colsum, colsumsq,
                                                        ss, clusters, batch, out);
}